// Round 1
// baseline (4380.613 us; speedup 1.0000x reference)
//
#include <hip/hip_runtime.h>

// ---------------------------------------------------------------------------
// GPT forward: 12 x (LN -> QKV GEMM -> causal flash attention -> proj+resid
//              -> LN -> FC+GELU -> FC2+resid) -> final LN
// B=4 T=1024 C=1024 H=16 D=64, L=12.  All GEMMs in bf16 MFMA (16x16x32),
// fp32 accumulate, fp32 residual stream. Weights converted+transposed to
// bf16 [N][K] per layer (MFMA B-fragment needs contraction-contiguous runs).
// ---------------------------------------------------------------------------

typedef __bf16 bf16x8 __attribute__((ext_vector_type(8)));
typedef float f32x4 __attribute__((ext_vector_type(4)));
typedef unsigned short u16x8 __attribute__((ext_vector_type(8)));

__device__ __forceinline__ unsigned short f2b(float f) {
    union { float f; unsigned u; } x{f};
    unsigned r = x.u + 0x7FFF + ((x.u >> 16) & 1);   // RNE
    return (unsigned short)(r >> 16);
}

__device__ __forceinline__ float gelu_f(float x) {
    // 0.5*x*(1+tanh(sqrt(2/pi)*(x+0.044715x^3))), tanh(u)=1-2/(e^{2u}+1)
    float u = 0.7978845608028654f * (x + 0.044715f * x * x * x);
    float t = __expf(2.f * u);
    float th = 1.f - 2.f / (t + 1.f);
    return 0.5f * x * (1.f + th);
}

// ---------------------------------------------------------------------------
// LayerNorm over C=1024. One block (256 thr) per row; each thread one float4.
// BF16OUT=1 -> bf16 out (GEMM A operand), else fp32 out (final output).
// ---------------------------------------------------------------------------
template <int BF16OUT>
__global__ __launch_bounds__(256) void ln_kernel(
    const float* __restrict__ x, const float* __restrict__ g,
    const float* __restrict__ bt, void* __restrict__ out) {
    const int row = blockIdx.x, tid = threadIdx.x;
    const float4 v = *(const float4*)(x + (size_t)row * 1024 + tid * 4);
    float s = v.x + v.y + v.z + v.w;
    float q = v.x * v.x + v.y * v.y + v.z * v.z + v.w * v.w;
    #pragma unroll
    for (int d = 1; d < 64; d <<= 1) { s += __shfl_xor(s, d); q += __shfl_xor(q, d); }
    __shared__ float ss[4], sq[4];
    const int w = tid >> 6;
    if ((tid & 63) == 0) { ss[w] = s; sq[w] = q; }
    __syncthreads();
    s = ss[0] + ss[1] + ss[2] + ss[3];
    q = sq[0] + sq[1] + sq[2] + sq[3];
    const float mean = s * (1.f / 1024.f);
    const float var = q * (1.f / 1024.f) - mean * mean;
    const float inv = rsqrtf(var + 1e-5f);
    const float4 gg = *(const float4*)(g + tid * 4);
    const float4 bb = *(const float4*)(bt + tid * 4);
    const float y0 = (v.x - mean) * inv * gg.x + bb.x;
    const float y1 = (v.y - mean) * inv * gg.y + bb.y;
    const float y2 = (v.z - mean) * inv * gg.z + bb.z;
    const float y3 = (v.w - mean) * inv * gg.w + bb.w;
    if (BF16OUT) {
        uint2 p;
        p.x = (unsigned)f2b(y0) | ((unsigned)f2b(y1) << 16);
        p.y = (unsigned)f2b(y2) | ((unsigned)f2b(y3) << 16);
        ((uint2*)out)[(size_t)row * 256 + tid] = p;
    } else {
        ((float4*)out)[(size_t)row * 256 + tid] = make_float4(y0, y1, y2, y3);
    }
}

// ---------------------------------------------------------------------------
// Weight convert+transpose: W fp32 [K][N] -> Wt bf16 [N][K].
// 64x64 tiles via LDS (pad 68 keeps float4 stores aligned).
// ---------------------------------------------------------------------------
__global__ __launch_bounds__(256) void wtrans_kernel(
    const float* __restrict__ W, unsigned short* __restrict__ Wt, int K, int N) {
    __shared__ float T[64][68];
    const int tid = threadIdx.x;
    const int n0 = blockIdx.x * 64, k0 = blockIdx.y * 64;
    #pragma unroll
    for (int r = 0; r < 4; ++r) {
        int li = tid + r * 256;
        int kk = li >> 4, nn = (li & 15) * 4;
        float4 v = *(const float4*)(W + (size_t)(k0 + kk) * N + n0 + nn);
        *(float4*)(&T[kk][nn]) = v;
    }
    __syncthreads();
    #pragma unroll
    for (int r = 0; r < 2; ++r) {
        int li = tid + r * 256;
        int nn = li >> 3, kc = li & 7;
        u16x8 t;
        #pragma unroll
        for (int j = 0; j < 8; ++j) t[j] = f2b(T[kc * 8 + j][nn]);
        *(u16x8*)(Wt + (size_t)(n0 + nn) * K + k0 + kc * 8) = t;
    }
}

// ---------------------------------------------------------------------------
// GEMM: C[M,N] = A[M,K](bf16) @ Bt[N,K]^T(bf16) + bias.
// MODE 0: store bf16.  MODE 1: GELU then bf16.  MODE 2: fp32 resid+store.
// 128x128 tile, BK=64, 4 waves each 64x64 (4x4 mfma_f32_16x16x32_bf16).
// LDS rows padded to 72 elems -> frag ds_read_b128 is 2-way (free, m136).
// ---------------------------------------------------------------------------
template <int MODE>
__global__ __launch_bounds__(256) void gemm_kernel(
    const unsigned short* __restrict__ A, const unsigned short* __restrict__ Bt,
    const float* __restrict__ bias, const float* __restrict__ resid,
    void* __restrict__ out, int M, int N, int K) {
    __shared__ unsigned short As[128 * 72];
    __shared__ unsigned short Bs[128 * 72];
    const int tid = threadIdx.x, lane = tid & 63, w = tid >> 6;
    const int wm = w >> 1, wn = w & 1, lr = lane & 15, quad = lane >> 4;
    const int m0 = blockIdx.y * 128, n0 = blockIdx.x * 128;
    f32x4 acc[4][4] = {};
    const int nk = K >> 6;
    for (int kt = 0; kt < nk; ++kt) {
        #pragma unroll
        for (int r = 0; r < 4; ++r) {
            int ci = tid + r * 256;
            int row = ci >> 3, c = ci & 7;
            *(uint4*)(&As[row * 72 + c * 8]) =
                *(const uint4*)(A + (size_t)(m0 + row) * K + kt * 64 + c * 8);
            *(uint4*)(&Bs[row * 72 + c * 8]) =
                *(const uint4*)(Bt + (size_t)(n0 + row) * K + kt * 64 + c * 8);
        }
        __syncthreads();
        #pragma unroll
        for (int s = 0; s < 2; ++s) {
            bf16x8 af[4], bf[4];
            #pragma unroll
            for (int i = 0; i < 4; ++i)
                af[i] = *(const bf16x8*)(&As[(wm * 64 + i * 16 + lr) * 72 + s * 32 + quad * 8]);
            #pragma unroll
            for (int j = 0; j < 4; ++j)
                bf[j] = *(const bf16x8*)(&Bs[(wn * 64 + j * 16 + lr) * 72 + s * 32 + quad * 8]);
            #pragma unroll
            for (int i = 0; i < 4; ++i)
                #pragma unroll
                for (int j = 0; j < 4; ++j)
                    acc[i][j] = __builtin_amdgcn_mfma_f32_16x16x32_bf16(af[i], bf[j], acc[i][j], 0, 0, 0);
        }
        __syncthreads();
    }
    // epilogue: C/D layout row=quad*4+r, col=lr within each 16x16 tile
    #pragma unroll
    for (int i = 0; i < 4; ++i) {
        #pragma unroll
        for (int j = 0; j < 4; ++j) {
            const int gm0 = m0 + wm * 64 + i * 16 + quad * 4;
            const int gn = n0 + wn * 64 + j * 16 + lr;
            const float bb = bias[gn];
            #pragma unroll
            for (int r = 0; r < 4; ++r) {
                float v = acc[i][j][r] + bb;
                const size_t idx = (size_t)(gm0 + r) * N + gn;
                if (MODE == 2) {
                    ((float*)out)[idx] = resid[idx] + v;
                } else {
                    if (MODE == 1) v = gelu_f(v);
                    ((unsigned short*)out)[idx] = f2b(v);
                }
            }
        }
    }
}

// ---------------------------------------------------------------------------
// Causal flash attention. Grid (T/64, B*H); block = 4 waves, wave w owns
// q rows [q0+16w, q0+16w+16). Iterates 64-wide K/V tiles up to the diagonal.
// K tile and V^T tile staged in LDS with XOR-chunk swizzle (conflict-free
// b128 frag reads). P goes C-layout -> LDS -> A-layout for the PV MFMA.
// ---------------------------------------------------------------------------
__global__ __launch_bounds__(256) void attn_kernel(
    const unsigned short* __restrict__ qkv, unsigned short* __restrict__ y) {
    __shared__ unsigned short Ks[64 * 64];
    __shared__ unsigned short Vt[64 * 64];
    __shared__ unsigned short Ps[4][16 * 64];
    const int tid = threadIdx.x, lane = tid & 63, w = tid >> 6;
    const int lr = lane & 15, quad = lane >> 4;
    const int bx = blockIdx.x, bh = blockIdx.y;
    const int b = bh >> 4, h = bh & 15;
    const int q0 = bx * 64;
    const unsigned short* base = qkv + (size_t)b * 1024 * 3072 + h * 64;

    bf16x8 qf[2];
    {
        const int qr = q0 + w * 16 + lr;
        qf[0] = *(const bf16x8*)(base + (size_t)qr * 3072 + quad * 8);
        qf[1] = *(const bf16x8*)(base + (size_t)qr * 3072 + 32 + quad * 8);
    }
    float m_r[4], l_r[4];
    f32x4 o[4] = {};
    #pragma unroll
    for (int r = 0; r < 4; ++r) { m_r[r] = -3e38f; l_r[r] = 0.f; }

    const int nkt = bx + 1;
    for (int kt = 0; kt < nkt; ++kt) {
        // stage K tile [64 kc][64 d], chunk-XOR swizzled
        #pragma unroll
        for (int r2 = 0; r2 < 2; ++r2) {
            int ci = tid + r2 * 256;
            int kr = ci >> 3, c = ci & 7;
            uint4 v = *(const uint4*)(base + (size_t)(kt * 64 + kr) * 3072 + 1024 + c * 8);
            *(uint4*)(&Ks[kr * 64 + ((c ^ (kr & 7)) << 3)]) = v;
        }
        // stage V transposed: Vt[d][kc], swizzled
        #pragma unroll
        for (int r2 = 0; r2 < 2; ++r2) {
            int vr = (tid >> 3) + r2 * 32;
            int c = (tid & 7) * 8;
            u16x8 v = *(const u16x8*)(base + (size_t)(kt * 64 + vr) * 3072 + 2048 + c);
            #pragma unroll
            for (int j = 0; j < 8; ++j) {
                int d = c + j;
                Vt[d * 64 + (((vr >> 3) ^ (d & 7)) << 3) + (vr & 7)] = v[j];
            }
        }
        __syncthreads();

        // S = (Q K^T) * 1/sqrt(D)
        f32x4 sf[4];
        #pragma unroll
        for (int jk = 0; jk < 4; ++jk) {
            f32x4 cf = {};
            #pragma unroll
            for (int s = 0; s < 2; ++s) {
                int krow = jk * 16 + lr;
                bf16x8 kf = *(const bf16x8*)(&Ks[krow * 64 + ((((s << 2) + quad) ^ (krow & 7)) << 3)]);
                cf = __builtin_amdgcn_mfma_f32_16x16x32_bf16(qf[s], kf, cf, 0, 0, 0);
            }
            #pragma unroll
            for (int r = 0; r < 4; ++r) sf[jk][r] = cf[r] * 0.125f;
        }
        if (kt == bx) {  // diagonal tile: causal mask
            #pragma unroll
            for (int jk = 0; jk < 4; ++jk)
                #pragma unroll
                for (int r = 0; r < 4; ++r) {
                    int kcol = q0 + jk * 16 + lr;
                    int qr = q0 + w * 16 + quad * 4 + r;
                    if (kcol > qr) sf[jk][r] = -3e38f;
                }
        }
        // online softmax (row stats across the 16 lanes of each quad)
        #pragma unroll
        for (int r = 0; r < 4; ++r) {
            float mx = fmaxf(fmaxf(sf[0][r], sf[1][r]), fmaxf(sf[2][r], sf[3][r]));
            #pragma unroll
            for (int d = 1; d < 16; d <<= 1) mx = fmaxf(mx, __shfl_xor(mx, d));
            const float mnew = fmaxf(m_r[r], mx);
            const float alpha = __expf(m_r[r] - mnew);
            float rs = 0.f;
            #pragma unroll
            for (int jk = 0; jk < 4; ++jk) {
                float p = __expf(sf[jk][r] - mnew);
                sf[jk][r] = p;
                rs += p;
            }
            #pragma unroll
            for (int d = 1; d < 16; d <<= 1) rs += __shfl_xor(rs, d);
            l_r[r] = l_r[r] * alpha + rs;
            m_r[r] = mnew;
            #pragma unroll
            for (int jd = 0; jd < 4; ++jd) o[jd][r] *= alpha;
        }
        // P: C-layout -> LDS (bf16, swizzled), then read back A-layout
        #pragma unroll
        for (int jk = 0; jk < 4; ++jk)
            #pragma unroll
            for (int r = 0; r < 4; ++r) {
                int row = quad * 4 + r;
                int col = jk * 16 + lr;
                Ps[w][row * 64 + (((col >> 3) ^ (row & 7)) << 3) + (col & 7)] = f2b(sf[jk][r]);
            }
        __syncthreads();
        // O += P V
        #pragma unroll
        for (int s2 = 0; s2 < 2; ++s2) {
            bf16x8 pf = *(const bf16x8*)(&Ps[w][lr * 64 + ((((s2 << 2) + quad) ^ (lr & 7)) << 3)]);
            #pragma unroll
            for (int jd = 0; jd < 4; ++jd) {
                int dr = jd * 16 + lr;
                bf16x8 vf = *(const bf16x8*)(&Vt[dr * 64 + ((((s2 << 2) + quad) ^ (dr & 7)) << 3)]);
                o[jd] = __builtin_amdgcn_mfma_f32_16x16x32_bf16(pf, vf, o[jd], 0, 0, 0);
            }
        }
        __syncthreads();
    }
    #pragma unroll
    for (int jd = 0; jd < 4; ++jd)
        #pragma unroll
        for (int r = 0; r < 4; ++r) {
            int qr = q0 + w * 16 + quad * 4 + r;
            int d = jd * 16 + lr;
            y[((size_t)b * 1024 + qr) * 1024 + h * 64 + d] = f2b(o[jd][r] / l_r[r]);
        }
}

// ---------------------------------------------------------------------------
// Host driver
// ---------------------------------------------------------------------------
extern "C" void kernel_launch(void* const* d_in, const int* in_sizes, int n_in,
                              void* d_out, int out_size, void* d_ws, size_t ws_size,
                              hipStream_t stream) {
    const float* x      = (const float*)d_in[0];
    const float* ln1_g  = (const float*)d_in[1];
    const float* ln1_b  = (const float*)d_in[2];
    const float* attn_w = (const float*)d_in[3];
    const float* attn_b = (const float*)d_in[4];
    const float* proj_w = (const float*)d_in[5];
    const float* proj_b = (const float*)d_in[6];
    const float* ln2_g  = (const float*)d_in[7];
    const float* ln2_b  = (const float*)d_in[8];
    const float* fc_w   = (const float*)d_in[9];
    const float* fc_b   = (const float*)d_in[10];
    const float* fc2_w  = (const float*)d_in[11];
    const float* fc2_b  = (const float*)d_in[12];
    const float* lnf_g  = (const float*)d_in[13];
    const float* lnf_b  = (const float*)d_in[14];

    char* ws = (char*)d_ws;
    float* xf            = (float*)ws;                              // 16 MB fp32 residual stream
    unsigned short* hbuf = (unsigned short*)(ws + (16u << 20));     //  8 MB LN output (bf16)
    unsigned short* qkvb = (unsigned short*)(ws + (24u << 20));     // 24 MB qkv (bf16)
    unsigned short* yb   = (unsigned short*)(ws + (48u << 20));     //  8 MB attn out (bf16)
    unsigned short* h2   = (unsigned short*)(ws + (56u << 20));     // 32 MB MLP hidden (bf16)
    unsigned short* wq   = (unsigned short*)(ws + (88u << 20));     //  6 MB attn_w^T bf16
    unsigned short* wp   = (unsigned short*)(ws + (94u << 20));     //  2 MB proj_w^T bf16
    unsigned short* wf   = (unsigned short*)(ws + (96u << 20));     //  8 MB fc_w^T bf16
    unsigned short* wf2  = (unsigned short*)(ws + (104u << 20));    //  8 MB fc2_w^T bf16

    hipMemcpyAsync(xf, x, (size_t)4096 * 1024 * 4, hipMemcpyDeviceToDevice, stream);

    for (int l = 0; l < 12; ++l) {
        wtrans_kernel<<<dim3(48, 16), 256, 0, stream>>>(attn_w + (size_t)l * 1024 * 3072, wq, 1024, 3072);
        wtrans_kernel<<<dim3(16, 16), 256, 0, stream>>>(proj_w + (size_t)l * 1024 * 1024, wp, 1024, 1024);
        wtrans_kernel<<<dim3(64, 16), 256, 0, stream>>>(fc_w + (size_t)l * 1024 * 4096, wf, 1024, 4096);
        wtrans_kernel<<<dim3(16, 64), 256, 0, stream>>>(fc2_w + (size_t)l * 4096 * 1024, wf2, 4096, 1024);

        ln_kernel<1><<<4096, 256, 0, stream>>>(xf, ln1_g + l * 1024, ln1_b + l * 1024, hbuf);
        gemm_kernel<0><<<dim3(24, 32), 256, 0, stream>>>(hbuf, wq, attn_b + l * 3072, nullptr,
                                                         qkvb, 4096, 3072, 1024);
        attn_kernel<<<dim3(16, 64), 256, 0, stream>>>(qkvb, yb);
        gemm_kernel<2><<<dim3(8, 32), 256, 0, stream>>>(yb, wp, proj_b + l * 1024, xf,
                                                        xf, 4096, 1024, 1024);
        ln_kernel<1><<<4096, 256, 0, stream>>>(xf, ln2_g + l * 1024, ln2_b + l * 1024, hbuf);
        gemm_kernel<1><<<dim3(32, 32), 256, 0, stream>>>(hbuf, wf, fc_b + l * 4096, nullptr,
                                                         h2, 4096, 4096, 1024);
        gemm_kernel<2><<<dim3(8, 32), 256, 0, stream>>>(h2, wf2, fc2_b + l * 1024, xf,
                                                        xf, 4096, 1024, 4096);
    }
    ln_kernel<0><<<4096, 256, 0, stream>>>(xf, lnf_g, lnf_b, d_out);
}

// Round 2
// 4376.777 us; speedup vs baseline: 1.0009x; 1.0009x over previous
//
#include <hip/hip_runtime.h>

// ---------------------------------------------------------------------------
// GPT forward: 12 x (LN -> QKV GEMM -> causal flash attention -> proj+resid
//              -> LN -> FC+GELU -> FC2+resid) -> final LN
// B=4 T=1024 C=1024 H=16 D=64, L=12.  All GEMMs in bf16 MFMA (16x16x32),
// fp32 accumulate, fp32 residual stream. Weights converted+transposed to
// bf16 [N][K] per layer (MFMA B-fragment needs contraction-contiguous runs).
//
// R1: GEMM staging via __builtin_amdgcn_global_load_lds width=16 (m97 lever,
// 517->874 TF on the ladder). LDS rows unpadded (64 shorts); bank conflicts
// avoided by XOR-chunk swizzle applied on the GLOBAL address side so the
// wave-uniform-base+lane*16 async write lands data pre-swizzled.
// ---------------------------------------------------------------------------

typedef __bf16 bf16x8 __attribute__((ext_vector_type(8)));
typedef float f32x4 __attribute__((ext_vector_type(4)));
typedef unsigned short u16x8 __attribute__((ext_vector_type(8)));

__device__ __forceinline__ unsigned short f2b(float f) {
    union { float f; unsigned u; } x{f};
    unsigned r = x.u + 0x7FFF + ((x.u >> 16) & 1);   // RNE
    return (unsigned short)(r >> 16);
}

__device__ __forceinline__ float gelu_f(float x) {
    // 0.5*x*(1+tanh(sqrt(2/pi)*(x+0.044715x^3))), tanh(u)=1-2/(e^{2u}+1)
    float u = 0.7978845608028654f * (x + 0.044715f * x * x * x);
    float t = __expf(2.f * u);
    float th = 1.f - 2.f / (t + 1.f);
    return 0.5f * x * (1.f + th);
}

// async 16B global -> LDS (wave-uniform LDS base, lane offset = lane*16)
__device__ __forceinline__ void g2l16(const unsigned short* g, unsigned short* l) {
    __builtin_amdgcn_global_load_lds(
        (const __attribute__((address_space(1))) void*)g,
        (__attribute__((address_space(3))) void*)l, 16, 0, 0);
}

// ---------------------------------------------------------------------------
// LayerNorm over C=1024. One block (256 thr) per row; each thread one float4.
// BF16OUT=1 -> bf16 out (GEMM A operand), else fp32 out (final output).
// ---------------------------------------------------------------------------
template <int BF16OUT>
__global__ __launch_bounds__(256) void ln_kernel(
    const float* __restrict__ x, const float* __restrict__ g,
    const float* __restrict__ bt, void* __restrict__ out) {
    const int row = blockIdx.x, tid = threadIdx.x;
    const float4 v = *(const float4*)(x + (size_t)row * 1024 + tid * 4);
    float s = v.x + v.y + v.z + v.w;
    float q = v.x * v.x + v.y * v.y + v.z * v.z + v.w * v.w;
    #pragma unroll
    for (int d = 1; d < 64; d <<= 1) { s += __shfl_xor(s, d); q += __shfl_xor(q, d); }
    __shared__ float ss[4], sq[4];
    const int w = tid >> 6;
    if ((tid & 63) == 0) { ss[w] = s; sq[w] = q; }
    __syncthreads();
    s = ss[0] + ss[1] + ss[2] + ss[3];
    q = sq[0] + sq[1] + sq[2] + sq[3];
    const float mean = s * (1.f / 1024.f);
    const float var = q * (1.f / 1024.f) - mean * mean;
    const float inv = rsqrtf(var + 1e-5f);
    const float4 gg = *(const float4*)(g + tid * 4);
    const float4 bb = *(const float4*)(bt + tid * 4);
    const float y0 = (v.x - mean) * inv * gg.x + bb.x;
    const float y1 = (v.y - mean) * inv * gg.y + bb.y;
    const float y2 = (v.z - mean) * inv * gg.z + bb.z;
    const float y3 = (v.w - mean) * inv * gg.w + bb.w;
    if (BF16OUT) {
        uint2 p;
        p.x = (unsigned)f2b(y0) | ((unsigned)f2b(y1) << 16);
        p.y = (unsigned)f2b(y2) | ((unsigned)f2b(y3) << 16);
        ((uint2*)out)[(size_t)row * 256 + tid] = p;
    } else {
        ((float4*)out)[(size_t)row * 256 + tid] = make_float4(y0, y1, y2, y3);
    }
}

// ---------------------------------------------------------------------------
// Weight convert+transpose: W fp32 [K][N] -> Wt bf16 [N][K].
// 64x64 tiles via LDS (pad 68 keeps float4 stores aligned).
// ---------------------------------------------------------------------------
__global__ __launch_bounds__(256) void wtrans_kernel(
    const float* __restrict__ W, unsigned short* __restrict__ Wt, int K, int N) {
    __shared__ float T[64][68];
    const int tid = threadIdx.x;
    const int n0 = blockIdx.x * 64, k0 = blockIdx.y * 64;
    #pragma unroll
    for (int r = 0; r < 4; ++r) {
        int li = tid + r * 256;
        int kk = li >> 4, nn = (li & 15) * 4;
        float4 v = *(const float4*)(W + (size_t)(k0 + kk) * N + n0 + nn);
        *(float4*)(&T[kk][nn]) = v;
    }
    __syncthreads();
    #pragma unroll
    for (int r = 0; r < 2; ++r) {
        int li = tid + r * 256;
        int nn = li >> 3, kc = li & 7;
        u16x8 t;
        #pragma unroll
        for (int j = 0; j < 8; ++j) t[j] = f2b(T[kc * 8 + j][nn]);
        *(u16x8*)(Wt + (size_t)(n0 + nn) * K + k0 + kc * 8) = t;
    }
}

// ---------------------------------------------------------------------------
// GEMM: C[M,N] = A[M,K](bf16) @ Bt[N,K]^T(bf16) + bias.
// MODE 0: store bf16.  MODE 1: GELU then bf16.  MODE 2: fp32 resid+store.
// 128x128 tile, BK=64, 4 waves each 64x64 (4x4 mfma_f32_16x16x32_bf16).
// Staging: global_load_lds dwordx4 (async, 1KB/wave-instr), 4 A + 4 B per
// wave per K-tile.  LDS layout: row-major 64-short rows, 8-elem chunks
// XOR-swizzled by (row&7); swizzle is pre-applied on the global address so
// the contiguous lane*16 async write lands data in swizzled position.
// Frag ds_read_b128 then hits all 8 chunks per quad -> 2-way only (free).
// ---------------------------------------------------------------------------
template <int MODE>
__global__ __launch_bounds__(256) void gemm_kernel(
    const unsigned short* __restrict__ A, const unsigned short* __restrict__ Bt,
    const float* __restrict__ bias, const float* __restrict__ resid,
    void* __restrict__ out, int M, int N, int K) {
    __shared__ unsigned short As[128 * 64];
    __shared__ unsigned short Bs[128 * 64];
    const int tid = threadIdx.x, lane = tid & 63, w = tid >> 6;
    const int wm = w >> 1, wn = w & 1, lr = lane & 15, quad = lane >> 4;
    const int m0 = blockIdx.y * 128, n0 = blockIdx.x * 128;

    // staging address: lane covers (row_in_seg = lane>>3, swizzled chunk)
    const int ar = lane >> 3;             // 0..7: row within 8-row segment
    const int ac = (lane & 7) ^ ar;       // chunk to FETCH so it lands swizzled
    const unsigned short* Ag = A  + (size_t)(m0 + w * 32 + ar) * K + ac * 8;
    const unsigned short* Bg = Bt + (size_t)(n0 + w * 32 + ar) * K + ac * 8;

    f32x4 acc[4][4] = {};
    const int nk = K >> 6;
    for (int kt = 0; kt < nk; ++kt) {
        #pragma unroll
        for (int r = 0; r < 4; ++r) {
            g2l16(Ag + (size_t)(r * 8) * K, &As[(w * 32 + r * 8) * 64]);
            g2l16(Bg + (size_t)(r * 8) * K, &Bs[(w * 32 + r * 8) * 64]);
        }
        Ag += 64; Bg += 64;
        __syncthreads();   // drains vmcnt (compiler emits waitcnt before barrier)
        #pragma unroll
        for (int s = 0; s < 2; ++s) {
            bf16x8 af[4], bf[4];
            #pragma unroll
            for (int i = 0; i < 4; ++i) {
                const int row = wm * 64 + i * 16 + lr;
                af[i] = *(const bf16x8*)(&As[row * 64 + ((((s << 2) + quad) ^ (lr & 7)) << 3)]);
            }
            #pragma unroll
            for (int j = 0; j < 4; ++j) {
                const int row = wn * 64 + j * 16 + lr;
                bf[j] = *(const bf16x8*)(&Bs[row * 64 + ((((s << 2) + quad) ^ (lr & 7)) << 3)]);
            }
            #pragma unroll
            for (int i = 0; i < 4; ++i)
                #pragma unroll
                for (int j = 0; j < 4; ++j)
                    acc[i][j] = __builtin_amdgcn_mfma_f32_16x16x32_bf16(af[i], bf[j], acc[i][j], 0, 0, 0);
        }
        __syncthreads();
    }
    // epilogue: C/D layout row=quad*4+r, col=lr within each 16x16 tile
    #pragma unroll
    for (int i = 0; i < 4; ++i) {
        #pragma unroll
        for (int j = 0; j < 4; ++j) {
            const int gm0 = m0 + wm * 64 + i * 16 + quad * 4;
            const int gn = n0 + wn * 64 + j * 16 + lr;
            const float bb = bias[gn];
            #pragma unroll
            for (int r = 0; r < 4; ++r) {
                float v = acc[i][j][r] + bb;
                const size_t idx = (size_t)(gm0 + r) * N + gn;
                if (MODE == 2) {
                    ((float*)out)[idx] = resid[idx] + v;
                } else {
                    if (MODE == 1) v = gelu_f(v);
                    ((unsigned short*)out)[idx] = f2b(v);
                }
            }
        }
    }
}

// ---------------------------------------------------------------------------
// Causal flash attention. Grid (T/64, B*H); block = 4 waves, wave w owns
// q rows [q0+16w, q0+16w+16). Iterates 64-wide K/V tiles up to the diagonal.
// K tile and V^T tile staged in LDS with XOR-chunk swizzle (conflict-free
// b128 frag reads). P goes C-layout -> LDS -> A-layout for the PV MFMA.
// ---------------------------------------------------------------------------
__global__ __launch_bounds__(256) void attn_kernel(
    const unsigned short* __restrict__ qkv, unsigned short* __restrict__ y) {
    __shared__ unsigned short Ks[64 * 64];
    __shared__ unsigned short Vt[64 * 64];
    __shared__ unsigned short Ps[4][16 * 64];
    const int tid = threadIdx.x, lane = tid & 63, w = tid >> 6;
    const int lr = lane & 15, quad = lane >> 4;
    const int bx = blockIdx.x, bh = blockIdx.y;
    const int b = bh >> 4, h = bh & 15;
    const int q0 = bx * 64;
    const unsigned short* base = qkv + (size_t)b * 1024 * 3072 + h * 64;

    bf16x8 qf[2];
    {
        const int qr = q0 + w * 16 + lr;
        qf[0] = *(const bf16x8*)(base + (size_t)qr * 3072 + quad * 8);
        qf[1] = *(const bf16x8*)(base + (size_t)qr * 3072 + 32 + quad * 8);
    }
    float m_r[4], l_r[4];
    f32x4 o[4] = {};
    #pragma unroll
    for (int r = 0; r < 4; ++r) { m_r[r] = -3e38f; l_r[r] = 0.f; }

    const int nkt = bx + 1;
    for (int kt = 0; kt < nkt; ++kt) {
        // stage K tile [64 kc][64 d], chunk-XOR swizzled
        #pragma unroll
        for (int r2 = 0; r2 < 2; ++r2) {
            int ci = tid + r2 * 256;
            int kr = ci >> 3, c = ci & 7;
            uint4 v = *(const uint4*)(base + (size_t)(kt * 64 + kr) * 3072 + 1024 + c * 8);
            *(uint4*)(&Ks[kr * 64 + ((c ^ (kr & 7)) << 3)]) = v;
        }
        // stage V transposed: Vt[d][kc], swizzled
        #pragma unroll
        for (int r2 = 0; r2 < 2; ++r2) {
            int vr = (tid >> 3) + r2 * 32;
            int c = (tid & 7) * 8;
            u16x8 v = *(const u16x8*)(base + (size_t)(kt * 64 + vr) * 3072 + 2048 + c);
            #pragma unroll
            for (int j = 0; j < 8; ++j) {
                int d = c + j;
                Vt[d * 64 + (((vr >> 3) ^ (d & 7)) << 3) + (vr & 7)] = v[j];
            }
        }
        __syncthreads();

        // S = (Q K^T) * 1/sqrt(D)
        f32x4 sf[4];
        #pragma unroll
        for (int jk = 0; jk < 4; ++jk) {
            f32x4 cf = {};
            #pragma unroll
            for (int s = 0; s < 2; ++s) {
                int krow = jk * 16 + lr;
                bf16x8 kf = *(const bf16x8*)(&Ks[krow * 64 + ((((s << 2) + quad) ^ (krow & 7)) << 3)]);
                cf = __builtin_amdgcn_mfma_f32_16x16x32_bf16(qf[s], kf, cf, 0, 0, 0);
            }
            #pragma unroll
            for (int r = 0; r < 4; ++r) sf[jk][r] = cf[r] * 0.125f;
        }
        if (kt == bx) {  // diagonal tile: causal mask
            #pragma unroll
            for (int jk = 0; jk < 4; ++jk)
                #pragma unroll
                for (int r = 0; r < 4; ++r) {
                    int kcol = q0 + jk * 16 + lr;
                    int qr = q0 + w * 16 + quad * 4 + r;
                    if (kcol > qr) sf[jk][r] = -3e38f;
                }
        }
        // online softmax (row stats across the 16 lanes of each quad)
        #pragma unroll
        for (int r = 0; r < 4; ++r) {
            float mx = fmaxf(fmaxf(sf[0][r], sf[1][r]), fmaxf(sf[2][r], sf[3][r]));
            #pragma unroll
            for (int d = 1; d < 16; d <<= 1) mx = fmaxf(mx, __shfl_xor(mx, d));
            const float mnew = fmaxf(m_r[r], mx);
            const float alpha = __expf(m_r[r] - mnew);
            float rs = 0.f;
            #pragma unroll
            for (int jk = 0; jk < 4; ++jk) {
                float p = __expf(sf[jk][r] - mnew);
                sf[jk][r] = p;
                rs += p;
            }
            #pragma unroll
            for (int d = 1; d < 16; d <<= 1) rs += __shfl_xor(rs, d);
            l_r[r] = l_r[r] * alpha + rs;
            m_r[r] = mnew;
            #pragma unroll
            for (int jd = 0; jd < 4; ++jd) o[jd][r] *= alpha;
        }
        // P: C-layout -> LDS (bf16, swizzled), then read back A-layout
        #pragma unroll
        for (int jk = 0; jk < 4; ++jk)
            #pragma unroll
            for (int r = 0; r < 4; ++r) {
                int row = quad * 4 + r;
                int col = jk * 16 + lr;
                Ps[w][row * 64 + (((col >> 3) ^ (row & 7)) << 3) + (col & 7)] = f2b(sf[jk][r]);
            }
        __syncthreads();
        // O += P V
        #pragma unroll
        for (int s2 = 0; s2 < 2; ++s2) {
            bf16x8 pf = *(const bf16x8*)(&Ps[w][lr * 64 + ((((s2 << 2) + quad) ^ (lr & 7)) << 3)]);
            #pragma unroll
            for (int jd = 0; jd < 4; ++jd) {
                int dr = jd * 16 + lr;
                bf16x8 vf = *(const bf16x8*)(&Vt[dr * 64 + ((((s2 << 2) + quad) ^ (dr & 7)) << 3)]);
                o[jd] = __builtin_amdgcn_mfma_f32_16x16x32_bf16(pf, vf, o[jd], 0, 0, 0);
            }
        }
        __syncthreads();
    }
    #pragma unroll
    for (int jd = 0; jd < 4; ++jd)
        #pragma unroll
        for (int r = 0; r < 4; ++r) {
            int qr = q0 + w * 16 + quad * 4 + r;
            int d = jd * 16 + lr;
            y[((size_t)b * 1024 + qr) * 1024 + h * 64 + d] = f2b(o[jd][r] / l_r[r]);
        }
}

// ---------------------------------------------------------------------------
// Host driver
// ---------------------------------------------------------------------------
extern "C" void kernel_launch(void* const* d_in, const int* in_sizes, int n_in,
                              void* d_out, int out_size, void* d_ws, size_t ws_size,
                              hipStream_t stream) {
    const float* x      = (const float*)d_in[0];
    const float* ln1_g  = (const float*)d_in[1];
    const float* ln1_b  = (const float*)d_in[2];
    const float* attn_w = (const float*)d_in[3];
    const float* attn_b = (const float*)d_in[4];
    const float* proj_w = (const float*)d_in[5];
    const float* proj_b = (const float*)d_in[6];
    const float* ln2_g  = (const float*)d_in[7];
    const float* ln2_b  = (const float*)d_in[8];
    const float* fc_w   = (const float*)d_in[9];
    const float* fc_b   = (const float*)d_in[10];
    const float* fc2_w  = (const float*)d_in[11];
    const float* fc2_b  = (const float*)d_in[12];
    const float* lnf_g  = (const float*)d_in[13];
    const float* lnf_b  = (const float*)d_in[14];

    char* ws = (char*)d_ws;
    float* xf            = (float*)ws;                              // 16 MB fp32 residual stream
    unsigned short* hbuf = (unsigned short*)(ws + (16u << 20));     //  8 MB LN output (bf16)
    unsigned short* qkvb = (unsigned short*)(ws + (24u << 20));     // 24 MB qkv (bf16)
    unsigned short* yb   = (unsigned short*)(ws + (48u << 20));     //  8 MB attn out (bf16)
    unsigned short* h2   = (unsigned short*)(ws + (56u << 20));     // 32 MB MLP hidden (bf16)
    unsigned short* wq   = (unsigned short*)(ws + (88u << 20));     //  6 MB attn_w^T bf16
    unsigned short* wp   = (unsigned short*)(ws + (94u << 20));     //  2 MB proj_w^T bf16
    unsigned short* wf   = (unsigned short*)(ws + (96u << 20));     //  8 MB fc_w^T bf16
    unsigned short* wf2  = (unsigned short*)(ws + (104u << 20));    //  8 MB fc2_w^T bf16

    hipMemcpyAsync(xf, x, (size_t)4096 * 1024 * 4, hipMemcpyDeviceToDevice, stream);

    for (int l = 0; l < 12; ++l) {
        wtrans_kernel<<<dim3(48, 16), 256, 0, stream>>>(attn_w + (size_t)l * 1024 * 3072, wq, 1024, 3072);
        wtrans_kernel<<<dim3(16, 16), 256, 0, stream>>>(proj_w + (size_t)l * 1024 * 1024, wp, 1024, 1024);
        wtrans_kernel<<<dim3(64, 16), 256, 0, stream>>>(fc_w + (size_t)l * 1024 * 4096, wf, 1024, 4096);
        wtrans_kernel<<<dim3(16, 64), 256, 0, stream>>>(fc2_w + (size_t)l * 4096 * 1024, wf2, 4096, 1024);

        ln_kernel<1><<<4096, 256, 0, stream>>>(xf, ln1_g + l * 1024, ln1_b + l * 1024, hbuf);
        gemm_kernel<0><<<dim3(24, 32), 256, 0, stream>>>(hbuf, wq, attn_b + l * 3072, nullptr,
                                                         qkvb, 4096, 3072, 1024);
        attn_kernel<<<dim3(16, 64), 256, 0, stream>>>(qkvb, yb);
        gemm_kernel<2><<<dim3(8, 32), 256, 0, stream>>>(yb, wp, proj_b + l * 1024, xf,
                                                        xf, 4096, 1024, 1024);
        ln_kernel<1><<<4096, 256, 0, stream>>>(xf, ln2_g + l * 1024, ln2_b + l * 1024, hbuf);
        gemm_kernel<1><<<dim3(32, 32), 256, 0, stream>>>(hbuf, wf, fc_b + l * 4096, nullptr,
                                                         h2, 4096, 4096, 1024);
        gemm_kernel<2><<<dim3(8, 32), 256, 0, stream>>>(h2, wf2, fc2_b + l * 1024, xf,
                                                        xf, 4096, 1024, 4096);
    }
    ln_kernel<0><<<4096, 256, 0, stream>>>(xf, lnf_g, lnf_b, d_out);
}

// Round 3
// 3833.756 us; speedup vs baseline: 1.1426x; 1.1416x over previous
//
#include <hip/hip_runtime.h>

// ---------------------------------------------------------------------------
// GPT forward: 12 x (LN -> QKV GEMM -> causal flash attention -> proj+resid
//              -> LN -> FC+GELU -> FC2+resid) -> final LN
// B=4 T=1024 C=1024 H=16 D=64, L=12.  All GEMMs in bf16 MFMA (16x16x32),
// fp32 accumulate, fp32 residual stream.
//
// R1: 128x128 MFMA GEMM, XOR-swizzled LDS.  R2: global_load_lds staging
// (neutral: K=1024 amortization + compiler pipelining already at plateau).
// R3: attention Q-tile 128 (staging/barriers per q-row halved, middle
// barrier removed - Ps is wave-private), 128x64-tile GEMM for N=1024
// (512 blocks = 2/CU -> inter-block overlap; 256 was 1/CU, barriers fully
// exposed), 4 wtrans merged into 1 dispatch.
// ---------------------------------------------------------------------------

typedef __bf16 bf16x8 __attribute__((ext_vector_type(8)));
typedef float f32x4 __attribute__((ext_vector_type(4)));
typedef unsigned short u16x8 __attribute__((ext_vector_type(8)));

#define L2E 1.4426950408889634f

__device__ __forceinline__ unsigned short f2b(float f) {
    union { float f; unsigned u; } x{f};
    unsigned r = x.u + 0x7FFF + ((x.u >> 16) & 1);   // RNE
    return (unsigned short)(r >> 16);
}

__device__ __forceinline__ float gelu_f(float x) {
    float u = 0.7978845608028654f * (x + 0.044715f * x * x * x);
    float t = __expf(2.f * u);
    float th = 1.f - 2.f / (t + 1.f);
    return 0.5f * x * (1.f + th);
}

// async 16B global -> LDS (wave-uniform LDS base, lane offset = lane*16)
__device__ __forceinline__ void g2l16(const unsigned short* g, unsigned short* l) {
    __builtin_amdgcn_global_load_lds(
        (const __attribute__((address_space(1))) void*)g,
        (__attribute__((address_space(3))) void*)l, 16, 0, 0);
}

// ---------------------------------------------------------------------------
// LayerNorm over C=1024. One block (256 thr) per row.
// ---------------------------------------------------------------------------
template <int BF16OUT>
__global__ __launch_bounds__(256) void ln_kernel(
    const float* __restrict__ x, const float* __restrict__ g,
    const float* __restrict__ bt, void* __restrict__ out) {
    const int row = blockIdx.x, tid = threadIdx.x;
    const float4 v = *(const float4*)(x + (size_t)row * 1024 + tid * 4);
    float s = v.x + v.y + v.z + v.w;
    float q = v.x * v.x + v.y * v.y + v.z * v.z + v.w * v.w;
    #pragma unroll
    for (int d = 1; d < 64; d <<= 1) { s += __shfl_xor(s, d); q += __shfl_xor(q, d); }
    __shared__ float ss[4], sq[4];
    const int w = tid >> 6;
    if ((tid & 63) == 0) { ss[w] = s; sq[w] = q; }
    __syncthreads();
    s = ss[0] + ss[1] + ss[2] + ss[3];
    q = sq[0] + sq[1] + sq[2] + sq[3];
    const float mean = s * (1.f / 1024.f);
    const float var = q * (1.f / 1024.f) - mean * mean;
    const float inv = rsqrtf(var + 1e-5f);
    const float4 gg = *(const float4*)(g + tid * 4);
    const float4 bb = *(const float4*)(bt + tid * 4);
    const float y0 = (v.x - mean) * inv * gg.x + bb.x;
    const float y1 = (v.y - mean) * inv * gg.y + bb.y;
    const float y2 = (v.z - mean) * inv * gg.z + bb.z;
    const float y3 = (v.w - mean) * inv * gg.w + bb.w;
    if (BF16OUT) {
        uint2 p;
        p.x = (unsigned)f2b(y0) | ((unsigned)f2b(y1) << 16);
        p.y = (unsigned)f2b(y2) | ((unsigned)f2b(y3) << 16);
        ((uint2*)out)[(size_t)row * 256 + tid] = p;
    } else {
        ((float4*)out)[(size_t)row * 256 + tid] = make_float4(y0, y1, y2, y3);
    }
}

// ---------------------------------------------------------------------------
// Weight convert+transpose, all 4 matrices of one layer in one dispatch.
// W fp32 [K][N] -> Wt bf16 [N][K] via 64x64 LDS tiles.
// Block ranges: [0,768) attn_w, [768,1024) proj_w, [1024,2048) fc_w,
// [2048,3072) fc2_w.
// ---------------------------------------------------------------------------
struct WT4 {
    const float *s0, *s1, *s2, *s3;
    unsigned short *d0, *d1, *d2, *d3;
};
__global__ __launch_bounds__(256) void wtrans4_kernel(WT4 p) {
    const int bid = blockIdx.x;
    const float* W; unsigned short* Wt; int K, N, lid, nx;
    if (bid < 768)       { W = p.s0; Wt = p.d0; K = 1024; N = 3072; lid = bid;        nx = 48; }
    else if (bid < 1024) { W = p.s1; Wt = p.d1; K = 1024; N = 1024; lid = bid - 768;  nx = 16; }
    else if (bid < 2048) { W = p.s2; Wt = p.d2; K = 1024; N = 4096; lid = bid - 1024; nx = 64; }
    else                 { W = p.s3; Wt = p.d3; K = 4096; N = 1024; lid = bid - 2048; nx = 16; }
    const int n0 = (lid % nx) * 64, k0 = (lid / nx) * 64;
    __shared__ float T[64][68];
    const int tid = threadIdx.x;
    #pragma unroll
    for (int r = 0; r < 4; ++r) {
        int li = tid + r * 256;
        int kk = li >> 4, nn = (li & 15) * 4;
        float4 v = *(const float4*)(W + (size_t)(k0 + kk) * N + n0 + nn);
        *(float4*)(&T[kk][nn]) = v;
    }
    __syncthreads();
    #pragma unroll
    for (int r = 0; r < 2; ++r) {
        int li = tid + r * 256;
        int nn = li >> 3, kc = li & 7;
        u16x8 t;
        #pragma unroll
        for (int j = 0; j < 8; ++j) t[j] = f2b(T[kc * 8 + j][nn]);
        *(u16x8*)(Wt + (size_t)(n0 + nn) * K + k0 + kc * 8) = t;
    }
}

// ---------------------------------------------------------------------------
// GEMM 128x128: C[M,N] = A[M,K](bf16) @ Bt[N,K]^T(bf16) + bias.
// MODE 0: store bf16.  MODE 1: GELU then bf16.  MODE 2: fp32 resid+store.
// global_load_lds staging, XOR-chunk swizzle pre-applied on global address.
// ---------------------------------------------------------------------------
template <int MODE>
__global__ __launch_bounds__(256) void gemm_kernel(
    const unsigned short* __restrict__ A, const unsigned short* __restrict__ Bt,
    const float* __restrict__ bias, const float* __restrict__ resid,
    void* __restrict__ out, int M, int N, int K) {
    __shared__ unsigned short As[128 * 64];
    __shared__ unsigned short Bs[128 * 64];
    const int tid = threadIdx.x, lane = tid & 63, w = tid >> 6;
    const int wm = w >> 1, wn = w & 1, lr = lane & 15, quad = lane >> 4;
    const int m0 = blockIdx.y * 128, n0 = blockIdx.x * 128;

    const int ar = lane >> 3;             // row within 8-row segment
    const int ac = (lane & 7) ^ ar;       // fetch chunk so it lands swizzled
    const unsigned short* Ag = A  + (size_t)(m0 + w * 32 + ar) * K + ac * 8;
    const unsigned short* Bg = Bt + (size_t)(n0 + w * 32 + ar) * K + ac * 8;

    f32x4 acc[4][4] = {};
    const int nk = K >> 6;
    for (int kt = 0; kt < nk; ++kt) {
        #pragma unroll
        for (int r = 0; r < 4; ++r) {
            g2l16(Ag + (size_t)(r * 8) * K, &As[(w * 32 + r * 8) * 64]);
            g2l16(Bg + (size_t)(r * 8) * K, &Bs[(w * 32 + r * 8) * 64]);
        }
        Ag += 64; Bg += 64;
        __syncthreads();
        #pragma unroll
        for (int s = 0; s < 2; ++s) {
            bf16x8 af[4], bf[4];
            #pragma unroll
            for (int i = 0; i < 4; ++i) {
                const int row = wm * 64 + i * 16 + lr;
                af[i] = *(const bf16x8*)(&As[row * 64 + ((((s << 2) + quad) ^ (lr & 7)) << 3)]);
            }
            #pragma unroll
            for (int j = 0; j < 4; ++j) {
                const int row = wn * 64 + j * 16 + lr;
                bf[j] = *(const bf16x8*)(&Bs[row * 64 + ((((s << 2) + quad) ^ (lr & 7)) << 3)]);
            }
            #pragma unroll
            for (int i = 0; i < 4; ++i)
                #pragma unroll
                for (int j = 0; j < 4; ++j)
                    acc[i][j] = __builtin_amdgcn_mfma_f32_16x16x32_bf16(af[i], bf[j], acc[i][j], 0, 0, 0);
        }
        __syncthreads();
    }
    #pragma unroll
    for (int i = 0; i < 4; ++i) {
        #pragma unroll
        for (int j = 0; j < 4; ++j) {
            const int gm0 = m0 + wm * 64 + i * 16 + quad * 4;
            const int gn = n0 + wn * 64 + j * 16 + lr;
            const float bb = bias[gn];
            #pragma unroll
            for (int r = 0; r < 4; ++r) {
                float v = acc[i][j][r] + bb;
                const size_t idx = (size_t)(gm0 + r) * N + gn;
                if (MODE == 2) {
                    ((float*)out)[idx] = resid[idx] + v;
                } else {
                    if (MODE == 1) v = gelu_f(v);
                    ((unsigned short*)out)[idx] = f2b(v);
                }
            }
        }
    }
}

// ---------------------------------------------------------------------------
// GEMM 128x64 (for N=1024 outputs: proj, fc2), MODE 2 (fp32 resid+store).
// 4 waves stacked in M (32 rows each); 512 blocks -> 2 blocks/CU overlap.
// ---------------------------------------------------------------------------
__global__ __launch_bounds__(256) void gemm64_kernel(
    const unsigned short* __restrict__ A, const unsigned short* __restrict__ Bt,
    const float* __restrict__ bias, const float* __restrict__ resid,
    float* __restrict__ out, int M, int N, int K) {
    __shared__ unsigned short As[128 * 64];
    __shared__ unsigned short Bs[64 * 64];
    const int tid = threadIdx.x, lane = tid & 63, w = tid >> 6;
    const int lr = lane & 15, quad = lane >> 4;
    const int m0 = blockIdx.y * 128, n0 = blockIdx.x * 64;

    const int ar = lane >> 3;
    const int ac = (lane & 7) ^ ar;
    const unsigned short* Ag = A  + (size_t)(m0 + w * 32 + ar) * K + ac * 8;
    const unsigned short* Bg = Bt + (size_t)(n0 + w * 16 + ar) * K + ac * 8;

    f32x4 acc[2][4] = {};
    const int nk = K >> 6;
    for (int kt = 0; kt < nk; ++kt) {
        #pragma unroll
        for (int r = 0; r < 4; ++r)
            g2l16(Ag + (size_t)(r * 8) * K, &As[(w * 32 + r * 8) * 64]);
        #pragma unroll
        for (int r = 0; r < 2; ++r)
            g2l16(Bg + (size_t)(r * 8) * K, &Bs[(w * 16 + r * 8) * 64]);
        Ag += 64; Bg += 64;
        __syncthreads();
        #pragma unroll
        for (int s = 0; s < 2; ++s) {
            bf16x8 af[2], bf[4];
            #pragma unroll
            for (int i = 0; i < 2; ++i) {
                const int row = w * 32 + i * 16 + lr;
                af[i] = *(const bf16x8*)(&As[row * 64 + ((((s << 2) + quad) ^ (lr & 7)) << 3)]);
            }
            #pragma unroll
            for (int j = 0; j < 4; ++j) {
                const int row = j * 16 + lr;
                bf[j] = *(const bf16x8*)(&Bs[row * 64 + ((((s << 2) + quad) ^ (lr & 7)) << 3)]);
            }
            #pragma unroll
            for (int i = 0; i < 2; ++i)
                #pragma unroll
                for (int j = 0; j < 4; ++j)
                    acc[i][j] = __builtin_amdgcn_mfma_f32_16x16x32_bf16(af[i], bf[j], acc[i][j], 0, 0, 0);
        }
        __syncthreads();
    }
    #pragma unroll
    for (int i = 0; i < 2; ++i) {
        #pragma unroll
        for (int j = 0; j < 4; ++j) {
            const int gm0 = m0 + w * 32 + i * 16 + quad * 4;
            const int gn = n0 + j * 16 + lr;
            const float bb = bias[gn];
            #pragma unroll
            for (int r = 0; r < 4; ++r) {
                const size_t idx = (size_t)(gm0 + r) * N + gn;
                out[idx] = resid[idx] + acc[i][j][r] + bb;
            }
        }
    }
}

// ---------------------------------------------------------------------------
// Causal flash attention, Q-tile 128. Grid (T/128, B*H); 4 waves, wave w owns
// q rows [q0+32w, q0+32w+32) as two 16-row fragments. K/V tiles 64 wide.
// 2 barriers per K-tile (Ps round-trip is wave-private -> no barrier).
// Waves skip fully-masked diagonal tiles.
// ---------------------------------------------------------------------------
__global__ __launch_bounds__(256) void attn_kernel(
    const unsigned short* __restrict__ qkv, unsigned short* __restrict__ y) {
    __shared__ unsigned short Ks[64 * 64];
    __shared__ unsigned short Vt[64 * 64];
    __shared__ unsigned short Ps[4][2][16 * 64];
    const int tid = threadIdx.x, lane = tid & 63, w = tid >> 6;
    const int lr = lane & 15, quad = lane >> 4;
    const int bx = blockIdx.x, bh = blockIdx.y;
    const int b = bh >> 4, h = bh & 15;
    const int q0 = bx * 128;
    const unsigned short* base = qkv + (size_t)b * 1024 * 3072 + h * 64;

    bf16x8 qf[2][2];
    #pragma unroll
    for (int i = 0; i < 2; ++i) {
        const int qr = q0 + w * 32 + i * 16 + lr;
        qf[i][0] = *(const bf16x8*)(base + (size_t)qr * 3072 + quad * 8);
        qf[i][1] = *(const bf16x8*)(base + (size_t)qr * 3072 + 32 + quad * 8);
    }
    float m_r[2][4], l_r[2][4];
    f32x4 o[2][4] = {};
    #pragma unroll
    for (int i = 0; i < 2; ++i)
        #pragma unroll
        for (int r = 0; r < 4; ++r) { m_r[i][r] = -3e38f; l_r[i][r] = 0.f; }

    const int nkt = 2 * bx + 2;
    for (int kt = 0; kt < nkt; ++kt) {
        // stage K tile [64 kc][64 d], chunk-XOR swizzled
        #pragma unroll
        for (int r2 = 0; r2 < 2; ++r2) {
            int ci = tid + r2 * 256;
            int kr = ci >> 3, c = ci & 7;
            uint4 v = *(const uint4*)(base + (size_t)(kt * 64 + kr) * 3072 + 1024 + c * 8);
            *(uint4*)(&Ks[kr * 64 + ((c ^ (kr & 7)) << 3)]) = v;
        }
        // stage V transposed: Vt[d][kc], swizzled
        #pragma unroll
        for (int r2 = 0; r2 < 2; ++r2) {
            int vr = (tid >> 3) + r2 * 32;
            int c = (tid & 7) * 8;
            u16x8 v = *(const u16x8*)(base + (size_t)(kt * 64 + vr) * 3072 + 2048 + c);
            #pragma unroll
            for (int j = 0; j < 8; ++j) {
                int d = c + j;
                Vt[d * 64 + (((vr >> 3) ^ (d & 7)) << 3) + (vr & 7)] = v[j];
            }
        }
        __syncthreads();

        #pragma unroll
        for (int i = 0; i < 2; ++i) {
            const int rowmin = q0 + w * 32 + i * 16;
            if (kt * 64 > rowmin + 15) continue;   // fully masked for this wave
            // S = (Q K^T) * 1/sqrt(D)
            f32x4 sf[4];
            #pragma unroll
            for (int jk = 0; jk < 4; ++jk) {
                f32x4 cf = {};
                #pragma unroll
                for (int s = 0; s < 2; ++s) {
                    int krow = jk * 16 + lr;
                    bf16x8 kf = *(const bf16x8*)(&Ks[krow * 64 + ((((s << 2) + quad) ^ (krow & 7)) << 3)]);
                    cf = __builtin_amdgcn_mfma_f32_16x16x32_bf16(qf[i][s], kf, cf, 0, 0, 0);
                }
                #pragma unroll
                for (int r = 0; r < 4; ++r) sf[jk][r] = cf[r] * 0.125f;
            }
            if (kt * 64 + 63 > rowmin) {  // diagonal tile: causal mask
                #pragma unroll
                for (int jk = 0; jk < 4; ++jk)
                    #pragma unroll
                    for (int r = 0; r < 4; ++r) {
                        int kcol = kt * 64 + jk * 16 + lr;
                        int qr = rowmin + quad * 4 + r;
                        if (kcol > qr) sf[jk][r] = -3e38f;
                    }
            }
            // online softmax (row stats across the 16 lanes of each quad)
            #pragma unroll
            for (int r = 0; r < 4; ++r) {
                float mx = fmaxf(fmaxf(sf[0][r], sf[1][r]), fmaxf(sf[2][r], sf[3][r]));
                #pragma unroll
                for (int d = 1; d < 16; d <<= 1) mx = fmaxf(mx, __shfl_xor(mx, d));
                const float mnew = fmaxf(m_r[i][r], mx);
                const float alpha = exp2f((m_r[i][r] - mnew) * L2E);
                float rs = 0.f;
                #pragma unroll
                for (int jk = 0; jk < 4; ++jk) {
                    float p = exp2f((sf[jk][r] - mnew) * L2E);
                    sf[jk][r] = p;
                    rs += p;
                }
                #pragma unroll
                for (int d = 1; d < 16; d <<= 1) rs += __shfl_xor(rs, d);
                l_r[i][r] = l_r[i][r] * alpha + rs;
                m_r[i][r] = mnew;
                #pragma unroll
                for (int jd = 0; jd < 4; ++jd) o[i][jd][r] *= alpha;
            }
            // P: C-layout -> LDS (wave-private; lgkmcnt ordering only)
            #pragma unroll
            for (int jk = 0; jk < 4; ++jk)
                #pragma unroll
                for (int r = 0; r < 4; ++r) {
                    int row = quad * 4 + r;
                    int col = jk * 16 + lr;
                    Ps[w][i][row * 64 + (((col >> 3) ^ (row & 7)) << 3) + (col & 7)] = f2b(sf[jk][r]);
                }
            // O += P V
            #pragma unroll
            for (int s2 = 0; s2 < 2; ++s2) {
                bf16x8 pf = *(const bf16x8*)(&Ps[w][i][lr * 64 + ((((s2 << 2) + quad) ^ (lr & 7)) << 3)]);
                #pragma unroll
                for (int jd = 0; jd < 4; ++jd) {
                    int dr = jd * 16 + lr;
                    bf16x8 vf = *(const bf16x8*)(&Vt[dr * 64 + ((((s2 << 2) + quad) ^ (dr & 7)) << 3)]);
                    o[i][jd] = __builtin_amdgcn_mfma_f32_16x16x32_bf16(pf, vf, o[i][jd], 0, 0, 0);
                }
            }
        }
        __syncthreads();
    }
    #pragma unroll
    for (int i = 0; i < 2; ++i)
        #pragma unroll
        for (int jd = 0; jd < 4; ++jd)
            #pragma unroll
            for (int r = 0; r < 4; ++r) {
                int qr = q0 + w * 32 + i * 16 + quad * 4 + r;
                int d = jd * 16 + lr;
                y[((size_t)b * 1024 + qr) * 1024 + h * 64 + d] = f2b(o[i][jd][r] / l_r[i][r]);
            }
}

// ---------------------------------------------------------------------------
// Host driver
// ---------------------------------------------------------------------------
extern "C" void kernel_launch(void* const* d_in, const int* in_sizes, int n_in,
                              void* d_out, int out_size, void* d_ws, size_t ws_size,
                              hipStream_t stream) {
    const float* x      = (const float*)d_in[0];
    const float* ln1_g  = (const float*)d_in[1];
    const float* ln1_b  = (const float*)d_in[2];
    const float* attn_w = (const float*)d_in[3];
    const float* attn_b = (const float*)d_in[4];
    const float* proj_w = (const float*)d_in[5];
    const float* proj_b = (const float*)d_in[6];
    const float* ln2_g  = (const float*)d_in[7];
    const float* ln2_b  = (const float*)d_in[8];
    const float* fc_w   = (const float*)d_in[9];
    const float* fc_b   = (const float*)d_in[10];
    const float* fc2_w  = (const float*)d_in[11];
    const float* fc2_b  = (const float*)d_in[12];
    const float* lnf_g  = (const float*)d_in[13];
    const float* lnf_b  = (const float*)d_in[14];

    char* ws = (char*)d_ws;
    float* xf            = (float*)ws;                              // 16 MB fp32 residual stream
    unsigned short* hbuf = (unsigned short*)(ws + (16u << 20));     //  8 MB LN output (bf16)
    unsigned short* qkvb = (unsigned short*)(ws + (24u << 20));     // 24 MB qkv (bf16)
    unsigned short* yb   = (unsigned short*)(ws + (48u << 20));     //  8 MB attn out (bf16)
    unsigned short* h2   = (unsigned short*)(ws + (56u << 20));     // 32 MB MLP hidden (bf16)
    unsigned short* wq   = (unsigned short*)(ws + (88u << 20));     //  6 MB attn_w^T bf16
    unsigned short* wp   = (unsigned short*)(ws + (94u << 20));     //  2 MB proj_w^T bf16
    unsigned short* wf   = (unsigned short*)(ws + (96u << 20));     //  8 MB fc_w^T bf16
    unsigned short* wf2  = (unsigned short*)(ws + (104u << 20));    //  8 MB fc2_w^T bf16

    hipMemcpyAsync(xf, x, (size_t)4096 * 1024 * 4, hipMemcpyDeviceToDevice, stream);

    for (int l = 0; l < 12; ++l) {
        WT4 p;
        p.s0 = attn_w + (size_t)l * 1024 * 3072;
        p.s1 = proj_w + (size_t)l * 1024 * 1024;
        p.s2 = fc_w   + (size_t)l * 1024 * 4096;
        p.s3 = fc2_w  + (size_t)l * 4096 * 1024;
        p.d0 = wq; p.d1 = wp; p.d2 = wf; p.d3 = wf2;
        wtrans4_kernel<<<3072, 256, 0, stream>>>(p);

        ln_kernel<1><<<4096, 256, 0, stream>>>(xf, ln1_g + l * 1024, ln1_b + l * 1024, hbuf);
        gemm_kernel<0><<<dim3(24, 32), 256, 0, stream>>>(hbuf, wq, attn_b + l * 3072, nullptr,
                                                         qkvb, 4096, 3072, 1024);
        attn_kernel<<<dim3(8, 64), 256, 0, stream>>>(qkvb, yb);
        gemm64_kernel<<<dim3(16, 32), 256, 0, stream>>>(yb, wp, proj_b + l * 1024, xf,
                                                        xf, 4096, 1024, 1024);
        ln_kernel<1><<<4096, 256, 0, stream>>>(xf, ln2_g + l * 1024, ln2_b + l * 1024, hbuf);
        gemm_kernel<1><<<dim3(32, 32), 256, 0, stream>>>(hbuf, wf, fc_b + l * 4096, nullptr,
                                                         h2, 4096, 4096, 1024);
        gemm64_kernel<<<dim3(16, 32), 256, 0, stream>>>(h2, wf2, fc2_b + l * 1024, xf,
                                                        xf, 4096, 1024, 4096);
    }
    ln_kernel<0><<<4096, 256, 0, stream>>>(xf, lnf_g, lnf_b, d_out);
}